// Round 1
// baseline (19.128 us; speedup 1.0000x reference)
//
#include <hip/hip_runtime.h>

// Problem constants (from reference setup_inputs):
// B=16, T=4, N=512, H=W=128, P=4096, D_LAT=128, row width = D_LAT+4 = 132
#define D_ROW   132
#define N_NODES 512
#define HH      128
#define WW      128
#define PP      4096
#define N_COEF_TOTAL 42   // 6*1 + 6*3 + 6*3

__global__ __launch_bounds__(256) void qtr_decoder_kernel(
    const float* __restrict__ nodes,   // (B,T,N,132)
    const int*   __restrict__ seg_ids, // (B,T,H,W)
    const int*   __restrict__ sp_inds, // (B,T,P,2)
    float*       __restrict__ out,     // (B,T,P,7)
    int total)                          // B*T*P
{
    int idx = blockIdx.x * blockDim.x + threadIdx.x;
    if (idx >= total) return;

    int bt = idx >> 12;                // idx / P  (P = 4096)

    // spatial indices (aligned int2)
    int2 si = ((const int2*)sp_inds)[idx];

    // segment gather
    int seg = seg_ids[(bt << 14) + si.x * WW + si.y];   // H*W = 16384
    float vseg = (seg >= 0 && seg < N_NODES) ? 1.0f : 0.0f;
    int sc = min(max(seg, 0), N_NODES - 1);

    // node row gather: floats [0..43] (coeffs 0..41) and [128..131] (hw + valid)
    const float4* rowp = (const float4*)(nodes + (size_t)(bt * N_NODES + sc) * D_ROW);
    float4 r[11];
#pragma unroll
    for (int i = 0; i < 11; ++i) r[i] = rowp[i];
    float4 tail = rowp[32];   // floats 128,129,130,131

    float c[44];
#pragma unroll
    for (int i = 0; i < 11; ++i) {
        c[4*i+0] = r[i].x; c[4*i+1] = r[i].y; c[4*i+2] = r[i].z; c[4*i+3] = r[i].w;
    }

    float vnode = (tail.w > 0.0f) ? 1.0f : 0.0f;
    float vdec  = vnode * vseg;

    // sif = -1 + spatial / ((H-1)/2)
    const float invScale = 2.0f / (HH - 1);   // H == W == 128
    float sifH = -1.0f + (float)si.x * invScale;
    float sifW = -1.0f + (float)si.y * invScale;
    float dH = sifH - tail.x;
    float dW = sifW - tail.y;

    float dlt[6] = { 1.0f, dH, dW, dH * dH, dH * dW, dW * dW };

    // pred_depths: coeffs 0..5
    float depth = 0.0f;
#pragma unroll
    for (int i = 0; i < 6; ++i) depth += c[i] * dlt[i];
    depth *= vdec;
    depth = fminf(depth, -0.1f);

    // pred_images: coeffs 6..23, 3 channels
    float img[3];
#pragma unroll
    for (int k = 0; k < 3; ++k) {
        float v = 0.0f;
#pragma unroll
        for (int i = 0; i < 6; ++i) v += c[6 + 3*i + k] * dlt[i];
        v *= vdec;
        img[k] = fminf(fmaxf(v, -100.0f), 100.0f);
    }

    // pred_normals: coeffs 24..41, 3 channels, l2-normalized
    float nrm[3];
    float ss = 0.0f;
#pragma unroll
    for (int k = 0; k < 3; ++k) {
        float v = 0.0f;
#pragma unroll
        for (int i = 0; i < 6; ++i) v += c[24 + 3*i + k] * dlt[i];
        v *= vdec;
        nrm[k] = v;
        ss += v * v;
    }
    float inv = 1.0f / sqrtf(fmaxf(ss, 1e-12f));
#pragma unroll
    for (int k = 0; k < 3; ++k) nrm[k] *= inv;

    // write 7 f32
    float* o = out + (size_t)idx * 7;
    o[0] = depth;
    o[1] = img[0]; o[2] = img[1]; o[3] = img[2];
    o[4] = nrm[0]; o[5] = nrm[1]; o[6] = nrm[2];
}

extern "C" void kernel_launch(void* const* d_in, const int* in_sizes, int n_in,
                              void* d_out, int out_size, void* d_ws, size_t ws_size,
                              hipStream_t stream) {
    const float* nodes = (const float*)d_in[0];
    const int*   seg   = (const int*)d_in[1];
    const int*   sp    = (const int*)d_in[2];
    float* out = (float*)d_out;

    int total = in_sizes[2] / 2;   // B*T*P
    int threads = 256;
    int blocks = (total + threads - 1) / threads;
    qtr_decoder_kernel<<<blocks, threads, 0, stream>>>(nodes, seg, sp, out, total);
}

// Round 2
// 16.335 us; speedup vs baseline: 1.1710x; 1.1710x over previous
//
#include <hip/hip_runtime.h>

// Problem constants (from reference setup_inputs):
// B=16, T=4, N=512, H=W=128, P=4096, D_LAT=128, row width = 132 floats
#define N_NODES 512
#define HH      128
#define WW      128
#define PP      4096
#define ROW_F4_SRC 33     // 132 floats = 33 float4 per source row
#define ROW_F4_LDS 13     // 12 staged float4 + 1 pad (8 distinct start banks)
#define LDS_BYTES  (N_NODES * ROW_F4_LDS * 16)   // 106,496 B

__global__ __launch_bounds__(256, 1) void qtr_decoder_lds_kernel(
    const float* __restrict__ nodes,   // (64, 512, 132)
    const int*   __restrict__ seg_ids, // (64, 128, 128)
    const int*   __restrict__ sp_inds, // (64, 4096, 2)
    float*       __restrict__ out)     // (64, 4096, 7)
{
    extern __shared__ float4 lds[];    // [512][13] float4

    const int blk     = blockIdx.x;    // 0..255
    const int bt      = blk >> 2;      // 0..63
    const int quarter = blk & 3;
    const int tid     = threadIdx.x;

    // ---- Stage node slice: 512 rows x 12 float4 (floats 0..43 and 128..131)
    const float4* nb = (const float4*)nodes + (size_t)bt * N_NODES * ROW_F4_SRC;
#pragma unroll
    for (int it = 0; it < 24; ++it) {
        int i = tid + it * 256;        // 0..6143
        int r = i / 12;
        int j = i - r * 12;
        int srcj = (j < 11) ? j : 32;
        lds[r * ROW_F4_LDS + j] = nb[r * ROW_F4_SRC + srcj];
    }
    __syncthreads();

    const int* segbt = seg_ids + (bt << 14);          // H*W = 16384
    const int pbase  = (bt << 12) + (quarter << 10);  // global point base

    // ---- Phase 1: gather spatial inds + segment ids for all 4 points
    int2 si[4];
    int  sg[4];
#pragma unroll
    for (int k = 0; k < 4; ++k) {
        int p = pbase + (k << 8) + tid;
        si[k] = ((const int2*)sp_inds)[p];
    }
#pragma unroll
    for (int k = 0; k < 4; ++k) {
        sg[k] = segbt[si[k].x * WW + si[k].y];
    }

    const float invScale = 2.0f / (HH - 1);

    // ---- Phase 2: per-point LDS gather + polynomial eval + store
#pragma unroll
    for (int k = 0; k < 4; ++k) {
        int p = pbase + (k << 8) + tid;
        int seg = sg[k];
        float vseg = (seg >= 0 && seg < N_NODES) ? 1.0f : 0.0f;
        int sc = min(max(seg, 0), N_NODES - 1);

        const float4* row = &lds[sc * ROW_F4_LDS];
        float4 r0 = row[0], r1 = row[1], r2 = row[2], r3 = row[3];
        float4 r4 = row[4], r5 = row[5], r6 = row[6], r7 = row[7];
        float4 r8 = row[8], r9 = row[9], r10 = row[10];
        float4 tail = row[11];           // floats 128,129,130,131

        float c[44];
        c[0]=r0.x; c[1]=r0.y; c[2]=r0.z; c[3]=r0.w;
        c[4]=r1.x; c[5]=r1.y; c[6]=r1.z; c[7]=r1.w;
        c[8]=r2.x; c[9]=r2.y; c[10]=r2.z; c[11]=r2.w;
        c[12]=r3.x; c[13]=r3.y; c[14]=r3.z; c[15]=r3.w;
        c[16]=r4.x; c[17]=r4.y; c[18]=r4.z; c[19]=r4.w;
        c[20]=r5.x; c[21]=r5.y; c[22]=r5.z; c[23]=r5.w;
        c[24]=r6.x; c[25]=r6.y; c[26]=r6.z; c[27]=r6.w;
        c[28]=r7.x; c[29]=r7.y; c[30]=r7.z; c[31]=r7.w;
        c[32]=r8.x; c[33]=r8.y; c[34]=r8.z; c[35]=r8.w;
        c[36]=r9.x; c[37]=r9.y; c[38]=r9.z; c[39]=r9.w;
        c[40]=r10.x; c[41]=r10.y; c[42]=r10.z; c[43]=r10.w;

        float vnode = (tail.w > 0.0f) ? 1.0f : 0.0f;
        float vdec  = vnode * vseg;

        float sifH = -1.0f + (float)si[k].x * invScale;
        float sifW = -1.0f + (float)si[k].y * invScale;
        float dH = sifH - tail.x;
        float dW = sifW - tail.y;

        float dlt[6] = { 1.0f, dH, dW, dH * dH, dH * dW, dW * dW };

        // pred_depths: coeffs 0..5
        float depth = 0.0f;
#pragma unroll
        for (int i = 0; i < 6; ++i) depth += c[i] * dlt[i];
        depth *= vdec;
        depth = fminf(depth, -0.1f);

        // pred_images: coeffs 6..23
        float img[3];
#pragma unroll
        for (int ch = 0; ch < 3; ++ch) {
            float v = 0.0f;
#pragma unroll
            for (int i = 0; i < 6; ++i) v += c[6 + 3*i + ch] * dlt[i];
            v *= vdec;
            img[ch] = fminf(fmaxf(v, -100.0f), 100.0f);
        }

        // pred_normals: coeffs 24..41, l2-normalized
        float nrm[3];
        float ss = 0.0f;
#pragma unroll
        for (int ch = 0; ch < 3; ++ch) {
            float v = 0.0f;
#pragma unroll
            for (int i = 0; i < 6; ++i) v += c[24 + 3*i + ch] * dlt[i];
            v *= vdec;
            nrm[ch] = v;
            ss += v * v;
        }
        float inv = 1.0f / sqrtf(fmaxf(ss, 1e-12f));
#pragma unroll
        for (int ch = 0; ch < 3; ++ch) nrm[ch] *= inv;

        float* o = out + (size_t)p * 7;
        o[0] = depth;
        o[1] = img[0]; o[2] = img[1]; o[3] = img[2];
        o[4] = nrm[0]; o[5] = nrm[1]; o[6] = nrm[2];
    }
}

extern "C" void kernel_launch(void* const* d_in, const int* in_sizes, int n_in,
                              void* d_out, int out_size, void* d_ws, size_t ws_size,
                              hipStream_t stream) {
    const float* nodes = (const float*)d_in[0];
    const int*   seg   = (const int*)d_in[1];
    const int*   sp    = (const int*)d_in[2];
    float* out = (float*)d_out;

    // 64 (b,t) slices x 4 blocks each; 256 threads x 4 points
    qtr_decoder_lds_kernel<<<256, 256, LDS_BYTES, stream>>>(nodes, seg, sp, out);
}